// Round 4
// baseline (388.123 us; speedup 1.0000x reference)
//
#include <hip/hip_runtime.h>
#include <cstdint>
#include <cstddef>

// Problem constants
#define B_ 2
#define S_ 2048
#define D_ 2048
#define H_ 16
#define HD_ 128
#define NTOK 4096       // B_*S_
#define NQKV 6144       // 3*D_

typedef unsigned short u16;
typedef __attribute__((ext_vector_type(8))) __bf16 bf16x8;
typedef __attribute__((ext_vector_type(4))) float f32x4;

// fp32 -> bf16 (RNE)
__device__ __forceinline__ u16 f2bf(float f) {
  uint32_t u = __builtin_bit_cast(uint32_t, f);
  u = (u + 0x7FFFu + ((u >> 16) & 1u)) >> 16;
  return (u16)u;
}

__device__ __forceinline__ void gload_lds16(const void* g, void* l) {
  __builtin_amdgcn_global_load_lds(
      (const __attribute__((address_space(1))) void*)g,
      (__attribute__((address_space(3))) void*)l, 16, 0, 0);
}

// ---------------- conversion kernel ----------------
__global__ void cvt_f32_bf16(const float* __restrict__ src, u16* __restrict__ dst, int n8) {
  int idx = blockIdx.x * blockDim.x + threadIdx.x;
  int stride = gridDim.x * blockDim.x;
  for (int i = idx; i < n8; i += stride) {
    const float4* s = (const float4*)(src + (size_t)i * 8);
    float4 a = s[0], b = s[1];
    union { u16 u[8]; uint4 v; } o;
    o.u[0] = f2bf(a.x); o.u[1] = f2bf(a.y); o.u[2] = f2bf(a.z); o.u[3] = f2bf(a.w);
    o.u[4] = f2bf(b.x); o.u[5] = f2bf(b.y); o.u[6] = f2bf(b.z); o.u[7] = f2bf(b.w);
    *(uint4*)(dst + (size_t)i * 8) = o.v;
  }
}

// ---------------- 2-phase 128^2 GEMM core (m97 structure, proven) ----------------
// C[m0..+127][n0..+127] += A[M][K] * B[N][K]^T (row-major bf16).
// 256 thr = 4 waves 2x2; per-wave 64x64 via 4x4 frags of 16x16x32.
__device__ __forceinline__ void gemm_bt_tile(
    const u16* __restrict__ A, const u16* __restrict__ B,
    int lda, int ldb, int K, int m0, int n0,
    u16* As, u16* Bs, f32x4 acc[4][4])
{
  const int tid = threadIdx.x;
  const int lane = tid & 63;
  const int wid = tid >> 6;
  const int wr = wid >> 1, wc = wid & 1;
  const int fr = lane & 15, fq = lane >> 4;

  for (int k0 = 0; k0 < K; k0 += 32) {
    __syncthreads();
#pragma unroll
    for (int i = 0; i < 2; ++i) {
      int cbase = (i * 4 + wid) * 64;
      int c = cbase + lane;
      int r = c >> 2, c8 = (c & 3) * 8;
      gload_lds16(A + (size_t)(m0 + r) * lda + k0 + c8, As + (size_t)cbase * 8);
      gload_lds16(B + (size_t)(n0 + r) * ldb + k0 + c8, Bs + (size_t)cbase * 8);
    }
    __syncthreads();

    bf16x8 a[4], b[4];
#pragma unroll
    for (int m = 0; m < 4; ++m)
      a[m] = *(const bf16x8*)&As[(wr * 64 + m * 16 + fr) * 32 + fq * 8];
#pragma unroll
    for (int n = 0; n < 4; ++n)
      b[n] = *(const bf16x8*)&Bs[(wc * 64 + n * 16 + fr) * 32 + fq * 8];
#pragma unroll
    for (int m = 0; m < 4; ++m)
#pragma unroll
      for (int n = 0; n < 4; ++n)
        acc[m][n] = __builtin_amdgcn_mfma_f32_16x16x32_bf16(a[m], b[n], acc[m][n], 0, 0, 0);
  }
}

// ---------------- QKV projection GEMM ----------------
// q pre-scaled by 1/sqrt(HD); scatter epilogue q,k (B,H,S,HD), vT (B,H,HD,S).
__global__ __launch_bounds__(256) void qkv_gemm(
    const u16* __restrict__ hsb, const u16* __restrict__ wb,
    const float* __restrict__ bias,
    u16* __restrict__ qb, u16* __restrict__ kb, u16* __restrict__ vT)
{
  __shared__ alignas(16) u16 As[128 * 32];
  __shared__ alignas(16) u16 Bs[128 * 32];
  f32x4 acc[4][4];
  f32x4 z = {0.f, 0.f, 0.f, 0.f};
#pragma unroll
  for (int m = 0; m < 4; ++m)
#pragma unroll
    for (int n = 0; n < 4; ++n) acc[m][n] = z;

  int m0 = blockIdx.x * 128, n0 = blockIdx.y * 128;
  gemm_bt_tile(hsb, wb, D_, D_, D_, m0, n0, As, Bs, acc);

  const float qscale = 0.08838834764831845f; // 1/sqrt(128)
  const int lane = threadIdx.x & 63;
  const int wid = threadIdx.x >> 6;
  const int wr = wid >> 1, wc = wid & 1;
  const int fr = lane & 15, fq = lane >> 4;
#pragma unroll
  for (int m = 0; m < 4; ++m)
#pragma unroll
    for (int n = 0; n < 4; ++n) {
      int col = n0 + wc * 64 + n * 16 + fr;       // 0..6143
      float bv = bias[col];
      int t = col >> 11;                           // 0=q 1=k 2=v (wave-uniform per frag)
      int d2 = col & 2047;
      int h = d2 >> 7, hd = d2 & 127;
#pragma unroll
      for (int r = 0; r < 4; ++r) {
        int row = m0 + wr * 64 + m * 16 + fq * 4 + r;   // 0..4095
        int bb = row >> 11, s = row & 2047;
        int bh = bb * H_ + h;
        float val = acc[m][n][r] + bv;
        if (t == 0)      qb[((size_t)bh * S_ + s) * HD_ + hd] = f2bf(val * qscale);
        else if (t == 1) kb[((size_t)bh * S_ + s) * HD_ + hd] = f2bf(val);
        else             vT[((size_t)bh * HD_ + hd) * S_ + s] = f2bf(val);
      }
    }
}

// ---------------- output projection GEMM ----------------
__global__ __launch_bounds__(256) void out_gemm(
    const u16* __restrict__ ctx, const u16* __restrict__ wo,
    const float* __restrict__ bias, float* __restrict__ out)
{
  __shared__ alignas(16) u16 As[128 * 32];
  __shared__ alignas(16) u16 Bs[128 * 32];
  f32x4 acc[4][4];
  f32x4 z = {0.f, 0.f, 0.f, 0.f};
#pragma unroll
  for (int m = 0; m < 4; ++m)
#pragma unroll
    for (int n = 0; n < 4; ++n) acc[m][n] = z;

  int m0 = blockIdx.x * 128, n0 = blockIdx.y * 128;
  gemm_bt_tile(ctx, wo, D_, D_, D_, m0, n0, As, Bs, acc);

  const int lane = threadIdx.x & 63;
  const int wid = threadIdx.x >> 6;
  const int wr = wid >> 1, wc = wid & 1;
  const int fr = lane & 15, fq = lane >> 4;
#pragma unroll
  for (int m = 0; m < 4; ++m)
#pragma unroll
    for (int n = 0; n < 4; ++n) {
      int col = n0 + wc * 64 + n * 16 + fr;
      float bv = bias[col];
#pragma unroll
      for (int r = 0; r < 4; ++r) {
        int row = m0 + wr * 64 + m * 16 + fq * 4 + r;
        out[(size_t)row * D_ + col] = acc[m][n][r] + bv;
      }
    }
}

// ---------------- flash attention v3 (v2 + T14 async-STAGE split) ----------------
// grid: (S/128, B*H). 256 thr = 4 waves; wave owns 32 q-rows. Swapped QK^T,
// defer-max THR=8. T14: next tile's K/V global loads issue right after the LDS
// publish barrier, so HBM latency hides under QK^T+softmax+PV; the vmcnt wait
// lands via register dependency before next iteration's LDS writes.
#define ALOAD(kvv) do { _Pragma("unroll") \
  for (int i = 0; i < 4; ++i) { \
    kreg[i] = *(const uint4*)(Kg + ((size_t)(kvv) + i * 16 + (tid >> 4)) * HD_ + (tid & 15) * 8); \
    vreg[i] = *(const uint4*)(Vg + (size_t)(i * 32 + (tid >> 3)) * S_ + (kvv) + (tid & 7) * 8); \
  } } while (0)

__global__ __launch_bounds__(256, 2) void attn(
    const u16* __restrict__ qb, const u16* __restrict__ kb,
    const u16* __restrict__ vT, u16* __restrict__ ctx)
{
  __shared__ alignas(16) u16 Kl[64 * 128];
  __shared__ alignas(16) u16 Vl[128 * 64];
  __shared__ alignas(16) u16 Pl[4][32 * 64];

  const int tid = threadIdx.x, lane = tid & 63, wid = tid >> 6;
  const int fr = lane & 15, fq = lane >> 4;
  const int bh = blockIdx.y;
  const int q0 = blockIdx.x * 128 + wid * 32;
  f32x4 z = {0.f, 0.f, 0.f, 0.f};

  const u16* qbase = qb + ((size_t)bh * S_ + q0) * HD_;
  bf16x8 qa[2][4];
#pragma unroll
  for (int h = 0; h < 2; ++h)
#pragma unroll
    for (int kc = 0; kc < 4; ++kc)
      qa[h][kc] = *(const bf16x8*)(qbase + (size_t)(h * 16 + fr) * HD_ + kc * 32 + fq * 8);

  f32x4 accv[2][8];
#pragma unroll
  for (int h = 0; h < 2; ++h)
#pragma unroll
    for (int n = 0; n < 8; ++n) accv[h][n] = z;
  float m_run[2] = {-1e30f, -1e30f};
  float l_run[2] = {0.f, 0.f};

  const u16* Kg = kb + (size_t)bh * S_ * HD_;
  const u16* Vg = vT + (size_t)bh * HD_ * S_;

  uint4 kreg[4], vreg[4];
  ALOAD(0);                       // prologue: tile-0 loads in flight

  for (int kv = 0; kv < S_; kv += 64) {
    __syncthreads();              // all waves done reading LDS (prev tile)
    // publish staged regs -> LDS, XOR-swizzled (vmcnt wait auto-inserted via dep)
#pragma unroll
    for (int i = 0; i < 4; ++i) {
      int row = i * 16 + (tid >> 4);
      *(uint4*)&Kl[row * 128 + (((tid & 15) * 8) ^ ((row & 7) << 3))] = kreg[i];
      int rv = i * 32 + (tid >> 3);
      *(uint4*)&Vl[rv * 64 + (((tid & 7) * 8) ^ ((rv & 7) << 3))] = vreg[i];
    }
    __syncthreads();              // LDS visible to all waves
    if (kv + 64 < S_) ALOAD(kv + 64);   // T14: overlap next tile's HBM with compute

    // QK^T swapped: sc[h][j][r] = S[k = j*16+fq*4+r][q = fr+16h] (q pre-scaled)
    f32x4 sc[2][4];
#pragma unroll
    for (int j = 0; j < 4; ++j) {
      f32x4 s0 = z, s1 = z;
#pragma unroll
      for (int kc = 0; kc < 4; ++kc) {
        int row = j * 16 + fr;
        bf16x8 kf = *(const bf16x8*)&Kl[row * 128 + ((kc * 32 + fq * 8) ^ ((row & 7) << 3))];
        s0 = __builtin_amdgcn_mfma_f32_16x16x32_bf16(kf, qa[0][kc], s0, 0, 0, 0);
        s1 = __builtin_amdgcn_mfma_f32_16x16x32_bf16(kf, qa[1][kc], s1, 0, 0, 0);
      }
      sc[0][j] = s0; sc[1][j] = s1;
    }

    float pmax[2];
#pragma unroll
    for (int h = 0; h < 2; ++h) {
      float mx = sc[h][0][0];
#pragma unroll
      for (int j = 0; j < 4; ++j)
#pragma unroll
        for (int r = 0; r < 4; ++r) mx = fmaxf(mx, sc[h][j][r]);
      mx = fmaxf(mx, __shfl_xor(mx, 16));
      mx = fmaxf(mx, __shfl_xor(mx, 32));
      pmax[h] = mx;
    }

    int need = (pmax[0] > m_run[0] + 8.f) || (pmax[1] > m_run[1] + 8.f);
    if (__any(need)) {
#pragma unroll
      for (int h = 0; h < 2; ++h) {
        float mn = fmaxf(m_run[h], pmax[h]);
        float corr = __expf(m_run[h] - mn);
        m_run[h] = mn;
        l_run[h] *= corr;
#pragma unroll
        for (int r = 0; r < 4; ++r) {
          float rc = __shfl(corr, (lane & 48) | (fq * 4 + r));
#pragma unroll
          for (int n = 0; n < 8; ++n) accv[h][n][r] *= rc;
        }
      }
    }

    u16* Pw = Pl[wid];
#pragma unroll
    for (int h = 0; h < 2; ++h) {
      float ls = 0.f;
#pragma unroll
      for (int j = 0; j < 4; ++j) {
        union { u16 u[4]; ushort4 v; } pk;
#pragma unroll
        for (int r = 0; r < 4; ++r) {
          float p = __expf(sc[h][j][r] - m_run[h]);
          ls += p;
          pk.u[r] = f2bf(p);
        }
        int prow = h * 16 + fr;
        *(ushort4*)&Pw[prow * 64 + ((j * 16 + fq * 4) ^ ((fr & 7) << 3))] = pk.v;
      }
      ls += __shfl_xor(ls, 16);
      ls += __shfl_xor(ls, 32);
      l_run[h] += ls;
    }

#pragma unroll
    for (int kc = 0; kc < 2; ++kc) {
      int pcol = (kc * 32 + fq * 8) ^ ((fr & 7) << 3);
      bf16x8 pa0 = *(const bf16x8*)&Pw[fr * 64 + pcol];
      bf16x8 pa1 = *(const bf16x8*)&Pw[(16 + fr) * 64 + pcol];
#pragma unroll
      for (int n = 0; n < 8; ++n) {
        int row = n * 16 + fr;
        bf16x8 vf = *(const bf16x8*)&Vl[row * 64 + ((kc * 32 + fq * 8) ^ ((row & 7) << 3))];
        accv[0][n] = __builtin_amdgcn_mfma_f32_16x16x32_bf16(pa0, vf, accv[0][n], 0, 0, 0);
        accv[1][n] = __builtin_amdgcn_mfma_f32_16x16x32_bf16(pa1, vf, accv[1][n], 0, 0, 0);
      }
    }
  }

  float inv[2][4];
#pragma unroll
  for (int h = 0; h < 2; ++h)
#pragma unroll
    for (int r = 0; r < 4; ++r) {
      float l = __shfl(l_run[h], (lane & 48) | (fq * 4 + r));
      inv[h][r] = 1.f / l;
    }
  u16* cb = ctx + (((size_t)(bh >> 4)) * S_ + blockIdx.x * 128 + wid * 32) * D_ + (size_t)(bh & 15) * HD_;
#pragma unroll
  for (int h = 0; h < 2; ++h)
#pragma unroll
    for (int n = 0; n < 8; ++n)
#pragma unroll
      for (int r = 0; r < 4; ++r) {
        int q = h * 16 + fq * 4 + r;
        cb[(size_t)q * D_ + n * 16 + fr] = f2bf(accv[h][n][r] * inv[h][r]);
      }
}

// ---------------- launcher ----------------
extern "C" void kernel_launch(void* const* d_in, const int* in_sizes, int n_in,
                              void* d_out, int out_size, void* d_ws, size_t ws_size,
                              hipStream_t stream) {
  const float* hs   = (const float*)d_in[0];
  const float* wqkv = (const float*)d_in[1];
  const float* bqkv = (const float*)d_in[2];
  const float* wo   = (const float*)d_in[3];
  const float* bo   = (const float*)d_in[4];
  float* out = (float*)d_out;

  char* ws = (char*)d_ws;
  u16* hsb   = (u16*)(ws);                      // 16.0 MiB  (4096*2048)
  u16* wqkvb = (u16*)(ws + 16777216);           // 24.0 MiB  (6144*2048)
  u16* wob   = (u16*)(ws + 41943040);           //  8.0 MiB  (2048*2048)
  u16* qb    = (u16*)(ws + 50331648);           // 16.0 MiB  (B,H,S,HD) pre-scaled
  u16* kb    = (u16*)(ws + 67108864);           // 16.0 MiB
  u16* vT    = (u16*)(ws + 83886080);           // 16.0 MiB  (B,H,HD,S)
  u16* ctx   = (u16*)(ws + 100663296);          // 16.0 MiB  (B,S,D)

  cvt_f32_bf16<<<2048, 256, 0, stream>>>(hs,   hsb,   (B_ * S_ * D_) / 8);
  cvt_f32_bf16<<<2048, 256, 0, stream>>>(wqkv, wqkvb, (NQKV * D_) / 8);
  cvt_f32_bf16<<<1024, 256, 0, stream>>>(wo,   wob,   (D_ * D_) / 8);

  qkv_gemm<<<dim3(NTOK / 128, NQKV / 128), 256, 0, stream>>>(hsb, wqkvb, bqkv, qb, kb, vT);
  attn<<<dim3(S_ / 128, B_ * H_), 256, 0, stream>>>(qb, kb, vT, ctx);
  out_gemm<<<dim3(NTOK / 128, D_ / 128), 256, 0, stream>>>(ctx, wob, bo, out);
}

// Round 5
// 307.075 us; speedup vs baseline: 1.2639x; 1.2639x over previous
//
#include <hip/hip_runtime.h>
#include <cstdint>
#include <cstddef>

// Problem constants
#define B_ 2
#define S_ 2048
#define D_ 2048
#define H_ 16
#define HD_ 128
#define NTOK 4096       // B_*S_
#define NQKV 6144       // 3*D_

typedef unsigned short u16;
typedef __attribute__((ext_vector_type(8))) __bf16 bf16x8;
typedef __attribute__((ext_vector_type(4))) float f32x4;

// fp32 -> bf16 (RNE)
__device__ __forceinline__ u16 f2bf(float f) {
  uint32_t u = __builtin_bit_cast(uint32_t, f);
  u = (u + 0x7FFFu + ((u >> 16) & 1u)) >> 16;
  return (u16)u;
}

__device__ __forceinline__ void gload_lds16(const void* g, void* l) {
  __builtin_amdgcn_global_load_lds(
      (const __attribute__((address_space(1))) void*)g,
      (__attribute__((address_space(3))) void*)l, 16, 0, 0);
}

// ---------------- conversion kernel ----------------
__global__ void cvt_f32_bf16(const float* __restrict__ src, u16* __restrict__ dst, int n8) {
  int idx = blockIdx.x * blockDim.x + threadIdx.x;
  int stride = gridDim.x * blockDim.x;
  for (int i = idx; i < n8; i += stride) {
    const float4* s = (const float4*)(src + (size_t)i * 8);
    float4 a = s[0], b = s[1];
    union { u16 u[8]; uint4 v; } o;
    o.u[0] = f2bf(a.x); o.u[1] = f2bf(a.y); o.u[2] = f2bf(a.z); o.u[3] = f2bf(a.w);
    o.u[4] = f2bf(b.x); o.u[5] = f2bf(b.y); o.u[6] = f2bf(b.z); o.u[7] = f2bf(b.w);
    *(uint4*)(dst + (size_t)i * 8) = o.v;
  }
}

// ---------------- 2-phase 128^2 GEMM core (m97 structure, proven 149us) ----------------
__device__ __forceinline__ void gemm_bt_tile(
    const u16* __restrict__ A, const u16* __restrict__ B,
    int lda, int ldb, int K, int m0, int n0,
    u16* As, u16* Bs, f32x4 acc[4][4])
{
  const int tid = threadIdx.x;
  const int lane = tid & 63;
  const int wid = tid >> 6;
  const int wr = wid >> 1, wc = wid & 1;
  const int fr = lane & 15, fq = lane >> 4;

  for (int k0 = 0; k0 < K; k0 += 32) {
    __syncthreads();
#pragma unroll
    for (int i = 0; i < 2; ++i) {
      int cbase = (i * 4 + wid) * 64;
      int c = cbase + lane;
      int r = c >> 2, c8 = (c & 3) * 8;
      gload_lds16(A + (size_t)(m0 + r) * lda + k0 + c8, As + (size_t)cbase * 8);
      gload_lds16(B + (size_t)(n0 + r) * ldb + k0 + c8, Bs + (size_t)cbase * 8);
    }
    __syncthreads();

    bf16x8 a[4], b[4];
#pragma unroll
    for (int m = 0; m < 4; ++m)
      a[m] = *(const bf16x8*)&As[(wr * 64 + m * 16 + fr) * 32 + fq * 8];
#pragma unroll
    for (int n = 0; n < 4; ++n)
      b[n] = *(const bf16x8*)&Bs[(wc * 64 + n * 16 + fr) * 32 + fq * 8];
#pragma unroll
    for (int m = 0; m < 4; ++m)
#pragma unroll
      for (int n = 0; n < 4; ++n)
        acc[m][n] = __builtin_amdgcn_mfma_f32_16x16x32_bf16(a[m], b[n], acc[m][n], 0, 0, 0);
  }
}

// ---------------- QKV projection GEMM ----------------
__global__ __launch_bounds__(256) void qkv_gemm(
    const u16* __restrict__ hsb, const u16* __restrict__ wb,
    const float* __restrict__ bias,
    u16* __restrict__ qb, u16* __restrict__ kb, u16* __restrict__ vT)
{
  __shared__ alignas(16) u16 As[128 * 32];
  __shared__ alignas(16) u16 Bs[128 * 32];
  f32x4 acc[4][4];
  f32x4 z = {0.f, 0.f, 0.f, 0.f};
#pragma unroll
  for (int m = 0; m < 4; ++m)
#pragma unroll
    for (int n = 0; n < 4; ++n) acc[m][n] = z;

  int m0 = blockIdx.x * 128, n0 = blockIdx.y * 128;
  gemm_bt_tile(hsb, wb, D_, D_, D_, m0, n0, As, Bs, acc);

  const float qscale = 0.08838834764831845f; // 1/sqrt(128)
  const int lane = threadIdx.x & 63;
  const int wid = threadIdx.x >> 6;
  const int wr = wid >> 1, wc = wid & 1;
  const int fr = lane & 15, fq = lane >> 4;
#pragma unroll
  for (int m = 0; m < 4; ++m)
#pragma unroll
    for (int n = 0; n < 4; ++n) {
      int col = n0 + wc * 64 + n * 16 + fr;       // 0..6143
      float bv = bias[col];
      int t = col >> 11;                           // 0=q 1=k 2=v
      int d2 = col & 2047;
      int h = d2 >> 7, hd = d2 & 127;
#pragma unroll
      for (int r = 0; r < 4; ++r) {
        int row = m0 + wr * 64 + m * 16 + fq * 4 + r;   // 0..4095
        int bb = row >> 11, s = row & 2047;
        int bh = bb * H_ + h;
        float val = acc[m][n][r] + bv;
        if (t == 0)      qb[((size_t)bh * S_ + s) * HD_ + hd] = f2bf(val * qscale);
        else if (t == 1) kb[((size_t)bh * S_ + s) * HD_ + hd] = f2bf(val);
        else             vT[((size_t)bh * HD_ + hd) * S_ + s] = f2bf(val);
      }
    }
}

// ---------------- output projection GEMM ----------------
__global__ __launch_bounds__(256) void out_gemm(
    const u16* __restrict__ ctx, const u16* __restrict__ wo,
    const float* __restrict__ bias, float* __restrict__ out)
{
  __shared__ alignas(16) u16 As[128 * 32];
  __shared__ alignas(16) u16 Bs[128 * 32];
  f32x4 acc[4][4];
  f32x4 z = {0.f, 0.f, 0.f, 0.f};
#pragma unroll
  for (int m = 0; m < 4; ++m)
#pragma unroll
    for (int n = 0; n < 4; ++n) acc[m][n] = z;

  int m0 = blockIdx.x * 128, n0 = blockIdx.y * 128;
  gemm_bt_tile(ctx, wo, D_, D_, D_, m0, n0, As, Bs, acc);

  const int lane = threadIdx.x & 63;
  const int wid = threadIdx.x >> 6;
  const int wr = wid >> 1, wc = wid & 1;
  const int fr = lane & 15, fq = lane >> 4;
#pragma unroll
  for (int m = 0; m < 4; ++m)
#pragma unroll
    for (int n = 0; n < 4; ++n) {
      int col = n0 + wc * 64 + n * 16 + fr;
      float bv = bias[col];
#pragma unroll
      for (int r = 0; r < 4; ++r) {
        int row = m0 + wr * 64 + m * 16 + fq * 4 + r;
        out[(size_t)row * D_ + col] = acc[m][n][r] + bv;
      }
    }
}

// ---------------- flash attention v4 ----------------
// v2 structure (swapped QK^T, defer-max, wave 32 q-rows) + zero-VGPR prefetch:
// K/V staged by global_load_lds into a DOUBLE buffer with pre-swizzled global
// source (linear LDS dest, swizzled read — rule #21; same mechanism as the
// GEMM staging, validated 0-conflict in-session). One barrier per tile: its
// implicit vmcnt(0) drains the prefetch issued at the top of the SAME
// iteration, so HBM latency hides under QK^T+softmax+PV with no register cost.
// Buffer ledger: stage into buf[cur^1] at tile t is safe — its last readers
// (tile t-1) were fenced by tile t-1's end barrier. LDS 80 KiB -> 2 blocks/CU.
#define STAGEKV(kvv, buf) do { _Pragma("unroll") \
  for (int i = 0; i < 4; ++i) { \
    int lk = i * 256 + tid; int rk = lk >> 4, sk = lk & 15; \
    gload_lds16(Kg + (size_t)((kvv) + rk) * HD_ + ((sk ^ (rk & 7)) << 3), \
                &Kl[buf][i * 2048 + wid * 512]); \
    int rv = lk >> 3, sv = lk & 7; \
    gload_lds16(Vg + (size_t)rv * S_ + (kvv) + ((sv ^ (rv & 7)) << 3), \
                &Vl[buf][i * 2048 + wid * 512]); \
  } } while (0)

__global__ __launch_bounds__(256, 2) void attn(
    const u16* __restrict__ qb, const u16* __restrict__ kb,
    const u16* __restrict__ vT, u16* __restrict__ ctx)
{
  __shared__ alignas(1024) u16 Kl[2][64 * 128];
  __shared__ alignas(1024) u16 Vl[2][128 * 64];
  __shared__ alignas(16) u16 Pl[4][32 * 64];

  const int tid = threadIdx.x, lane = tid & 63, wid = tid >> 6;
  const int fr = lane & 15, fq = lane >> 4;
  const int bh = blockIdx.y;
  const int q0 = blockIdx.x * 128 + wid * 32;
  f32x4 z = {0.f, 0.f, 0.f, 0.f};

  const u16* Kg = kb + (size_t)bh * S_ * HD_;
  const u16* Vg = vT + (size_t)bh * HD_ * S_;

  STAGEKV(0, 0);                 // tile-0 K/V in flight (no VGPRs)

  // Q fragments (B-operand layout), once
  const u16* qbase = qb + ((size_t)bh * S_ + q0) * HD_;
  bf16x8 qa[2][4];
#pragma unroll
  for (int h = 0; h < 2; ++h)
#pragma unroll
    for (int kc = 0; kc < 4; ++kc)
      qa[h][kc] = *(const bf16x8*)(qbase + (size_t)(h * 16 + fr) * HD_ + kc * 32 + fq * 8);

  f32x4 accv[2][8];
#pragma unroll
  for (int h = 0; h < 2; ++h)
#pragma unroll
    for (int n = 0; n < 8; ++n) accv[h][n] = z;
  float m_run[2] = {-1e30f, -1e30f};
  float l_run[2] = {0.f, 0.f};

  __syncthreads();               // vmcnt(0) drain: tile-0 staged, visible to all
  int cur = 0;

  for (int kv = 0; kv < S_; kv += 64) {
    if (kv + 64 < S_) STAGEKV(kv + 64, cur ^ 1);   // prefetch next tile

    const u16* Kc = Kl[cur];
    const u16* Vc = Vl[cur];

    // QK^T swapped: sc[h][j][r] = S[k = j*16+fq*4+r][q = fr+16h] (q pre-scaled)
    f32x4 sc[2][4];
#pragma unroll
    for (int j = 0; j < 4; ++j) {
      f32x4 s0 = z, s1 = z;
#pragma unroll
      for (int kc = 0; kc < 4; ++kc) {
        int row = j * 16 + fr;
        bf16x8 kf = *(const bf16x8*)&Kc[row * 128 + ((kc * 32 + fq * 8) ^ ((row & 7) << 3))];
        s0 = __builtin_amdgcn_mfma_f32_16x16x32_bf16(kf, qa[0][kc], s0, 0, 0, 0);
        s1 = __builtin_amdgcn_mfma_f32_16x16x32_bf16(kf, qa[1][kc], s1, 0, 0, 0);
      }
      sc[0][j] = s0; sc[1][j] = s1;
    }

    float pmax[2];
#pragma unroll
    for (int h = 0; h < 2; ++h) {
      float mx = sc[h][0][0];
#pragma unroll
      for (int j = 0; j < 4; ++j)
#pragma unroll
        for (int r = 0; r < 4; ++r) mx = fmaxf(mx, sc[h][j][r]);
      mx = fmaxf(mx, __shfl_xor(mx, 16));
      mx = fmaxf(mx, __shfl_xor(mx, 32));
      pmax[h] = mx;
    }

    int need = (pmax[0] > m_run[0] + 8.f) || (pmax[1] > m_run[1] + 8.f);
    if (__any(need)) {
#pragma unroll
      for (int h = 0; h < 2; ++h) {
        float mn = fmaxf(m_run[h], pmax[h]);
        float corr = __expf(m_run[h] - mn);
        m_run[h] = mn;
        l_run[h] *= corr;
#pragma unroll
        for (int r = 0; r < 4; ++r) {
          float rc = __shfl(corr, (lane & 48) | (fq * 4 + r));
#pragma unroll
          for (int n = 0; n < 8; ++n) accv[h][n][r] *= rc;
        }
      }
    }

    u16* Pw = Pl[wid];
#pragma unroll
    for (int h = 0; h < 2; ++h) {
      float ls = 0.f;
#pragma unroll
      for (int j = 0; j < 4; ++j) {
        union { u16 u[4]; ushort4 v; } pk;
#pragma unroll
        for (int r = 0; r < 4; ++r) {
          float p = __expf(sc[h][j][r] - m_run[h]);
          ls += p;
          pk.u[r] = f2bf(p);
        }
        int prow = h * 16 + fr;
        *(ushort4*)&Pw[prow * 64 + ((j * 16 + fq * 4) ^ ((fr & 7) << 3))] = pk.v;
      }
      ls += __shfl_xor(ls, 16);
      ls += __shfl_xor(ls, 32);
      l_run[h] += ls;
    }

#pragma unroll
    for (int kc = 0; kc < 2; ++kc) {
      int pcol = (kc * 32 + fq * 8) ^ ((fr & 7) << 3);
      bf16x8 pa0 = *(const bf16x8*)&Pw[fr * 64 + pcol];
      bf16x8 pa1 = *(const bf16x8*)&Pw[(16 + fr) * 64 + pcol];
#pragma unroll
      for (int n = 0; n < 8; ++n) {
        int row = n * 16 + fr;
        bf16x8 vf = *(const bf16x8*)&Vc[row * 64 + ((kc * 32 + fq * 8) ^ ((row & 7) << 3))];
        accv[0][n] = __builtin_amdgcn_mfma_f32_16x16x32_bf16(pa0, vf, accv[0][n], 0, 0, 0);
        accv[1][n] = __builtin_amdgcn_mfma_f32_16x16x32_bf16(pa1, vf, accv[1][n], 0, 0, 0);
      }
    }

    __syncthreads();             // drains prefetch (vmcnt 0) + closes buf[cur] reads
    cur ^= 1;
  }

  float inv[2][4];
#pragma unroll
  for (int h = 0; h < 2; ++h)
#pragma unroll
    for (int r = 0; r < 4; ++r) {
      float l = __shfl(l_run[h], (lane & 48) | (fq * 4 + r));
      inv[h][r] = 1.f / l;
    }
  u16* cb = ctx + (((size_t)(bh >> 4)) * S_ + blockIdx.x * 128 + wid * 32) * D_ + (size_t)(bh & 15) * HD_;
#pragma unroll
  for (int h = 0; h < 2; ++h)
#pragma unroll
    for (int n = 0; n < 8; ++n)
#pragma unroll
      for (int r = 0; r < 4; ++r) {
        int q = h * 16 + fq * 4 + r;
        cb[(size_t)q * D_ + n * 16 + fr] = f2bf(accv[h][n][r] * inv[h][r]);
      }
}

// ---------------- launcher ----------------
extern "C" void kernel_launch(void* const* d_in, const int* in_sizes, int n_in,
                              void* d_out, int out_size, void* d_ws, size_t ws_size,
                              hipStream_t stream) {
  const float* hs   = (const float*)d_in[0];
  const float* wqkv = (const float*)d_in[1];
  const float* bqkv = (const float*)d_in[2];
  const float* wo   = (const float*)d_in[3];
  const float* bo   = (const float*)d_in[4];
  float* out = (float*)d_out;

  char* ws = (char*)d_ws;
  u16* hsb   = (u16*)(ws);                      // 16.0 MiB  (4096*2048)
  u16* wqkvb = (u16*)(ws + 16777216);           // 24.0 MiB  (6144*2048)
  u16* wob   = (u16*)(ws + 41943040);           //  8.0 MiB  (2048*2048)
  u16* qb    = (u16*)(ws + 50331648);           // 16.0 MiB  (B,H,S,HD) pre-scaled
  u16* kb    = (u16*)(ws + 67108864);           // 16.0 MiB
  u16* vT    = (u16*)(ws + 83886080);           // 16.0 MiB  (B,H,HD,S)
  u16* ctx   = (u16*)(ws + 100663296);          // 16.0 MiB  (B,S,D)

  cvt_f32_bf16<<<2048, 256, 0, stream>>>(hs,   hsb,   (B_ * S_ * D_) / 8);
  cvt_f32_bf16<<<2048, 256, 0, stream>>>(wqkv, wqkvb, (NQKV * D_) / 8);
  cvt_f32_bf16<<<1024, 256, 0, stream>>>(wo,   wob,   (D_ * D_) / 8);

  qkv_gemm<<<dim3(NTOK / 128, NQKV / 128), 256, 0, stream>>>(hsb, wqkvb, bqkv, qb, kb, vT);
  attn<<<dim3(S_ / 128, B_ * H_), 256, 0, stream>>>(qb, kb, vT, ctx);
  out_gemm<<<dim3(NTOK / 128, D_ / 128), 256, 0, stream>>>(ctx, wob, bo, out);
}